// Round 7
// baseline (608.120 us; speedup 1.0000x reference)
//
#include <hip/hip_runtime.h>

// GraphSAGE mean-aggregate + linear (no bias): out = segment_mean(x[src] by dst) @ W^T
// x: [50000, 64] f32, edge_index: [2, 800000] int32, W: [128, 64] f32,
// out: [50000, 128] f32.
//
// Pipeline (3 dispatches):
//   prep (transpose W -> wt4, zero cursor)
//   bin  (bucket sort by dst/49 into 1024 buckets, LDS-staged, coalesced)
//   fused (per bucket: LDS float-atomic scatter-accumulate of x rows,
//          then mean + W^T epilogue from coalesced wt4, direct out write).

constexpr int N_NODES = 50000;
constexpr int N_EDGES = 800000;
constexpr int IN_CH   = 64;
constexpr int HID_CH  = 128;

constexpr int NBKT    = 1024;
constexpr int NPB     = 49;          // nodes per bucket; 1024*49 = 50176 >= 50000
constexpr int BKT_CAP = 1024;        // mean 781, sigma ~28 -> +8.7 sigma headroom
constexpr int CHUNK   = 4096;        // edges per binning block
constexpr int NBIN    = (N_EDGES + CHUNK - 1) / CHUNK;  // 196
constexpr int LSTRIDE = 68;          // lsum row stride (floats): 16B-aligned, +4 bank shift/row

// ---- prep: W[128][64] -> wt4[k4][o] (coalesced-epilogue layout); zero cursor ----
__global__ __launch_bounds__(256) void prep_kernel(
    const float* __restrict__ W, float4* __restrict__ wt4, int* __restrict__ cursor)
{
    const int t = threadIdx.x;
    if (blockIdx.x < 8) {
        const int j  = blockIdx.x * 256 + t;   // [0, 2048)
        const int k4 = j >> 7, o = j & 127;
        wt4[j] = *reinterpret_cast<const float4*>(W + (size_t)o * IN_CH + k4 * 4);
    } else {
        #pragma unroll
        for (int i = 0; i < 4; ++i) cursor[t * 4 + i] = 0;
    }
}

// ---- bin: bucket-bin edges into 1024 buckets. LDS histogram + local sort,
//      coalesced write-out; rotated global-cursor reservation order ----
__global__ __launch_bounds__(256) void bin_kernel(
    const int* __restrict__ ei,
    int* __restrict__ cursor,                       // [NBKT], zeroed by prep
    unsigned long long* __restrict__ binned)        // [NBKT][BKT_CAP] (dst<<32)|src
{
    __shared__ int hist[NBKT];
    __shared__ int lexcl[NBKT];
    __shared__ int lcur[NBKT];
    __shared__ int res[NBKT];
    __shared__ int scan2[256];
    __shared__ unsigned long long stage[CHUNK];

    const int t  = threadIdx.x;
    const int e0 = blockIdx.x * CHUNK;
    const int nE = min(N_EDGES - e0, CHUNK);

    #pragma unroll
    for (int i = 0; i < 4; ++i) hist[t + i * 256] = 0;
    __syncthreads();

    int srcs[16], dsts[16];
    #pragma unroll
    for (int q = 0; q < 4; ++q) {
        const int idx = t * 16 + q * 4;
        if (idx < nE) {  // nE % 4 == 0 always (last block: 1280)
            const int4 s4 = *reinterpret_cast<const int4*>(ei + e0 + idx);
            const int4 d4 = *reinterpret_cast<const int4*>(ei + N_EDGES + e0 + idx);
            srcs[q * 4 + 0] = s4.x; srcs[q * 4 + 1] = s4.y;
            srcs[q * 4 + 2] = s4.z; srcs[q * 4 + 3] = s4.w;
            dsts[q * 4 + 0] = d4.x; dsts[q * 4 + 1] = d4.y;
            dsts[q * 4 + 2] = d4.z; dsts[q * 4 + 3] = d4.w;
            atomicAdd(&hist[d4.x / NPB], 1);
            atomicAdd(&hist[d4.y / NPB], 1);
            atomicAdd(&hist[d4.z / NPB], 1);
            atomicAdd(&hist[d4.w / NPB], 1);
        } else {
            srcs[q*4+0]=srcs[q*4+1]=srcs[q*4+2]=srcs[q*4+3]=0;
            dsts[q*4+0]=dsts[q*4+1]=dsts[q*4+2]=dsts[q*4+3]=0;
        }
    }
    __syncthreads();

    // Exclusive scan over 1024 buckets: thread t owns buckets 4t..4t+3.
    const int b0 = t * 4;
    const int h0 = hist[b0], h1 = hist[b0 + 1], h2 = hist[b0 + 2], h3 = hist[b0 + 3];
    const int hs = h0 + h1 + h2 + h3;
    scan2[t] = hs;
    __syncthreads();
    for (int off = 1; off < 256; off <<= 1) {
        const int u = (t >= off) ? scan2[t - off] : 0;
        __syncthreads();
        scan2[t] += u;
        __syncthreads();
    }
    const int base = scan2[t] - hs;
    lexcl[b0]     = base;               lcur[b0]     = base;
    lexcl[b0 + 1] = base + h0;          lcur[b0 + 1] = base + h0;
    lexcl[b0 + 2] = base + h0 + h1;     lcur[b0 + 2] = base + h0 + h1;
    lexcl[b0 + 3] = base + h0 + h1 + h2; lcur[b0 + 3] = base + h0 + h1 + h2;

    // Reserve global space; rotate visit order to spread atomic contention.
    const int rot = (blockIdx.x * 97) & (NBKT - 1);
    #pragma unroll
    for (int i = 0; i < 4; ++i) {
        const int b = (b0 + i + rot) & (NBKT - 1);
        const int hv = hist[b];
        res[b] = (hv > 0) ? atomicAdd(&cursor[b], hv) : 0;
    }
    __syncthreads();

    // Local sort into stage (bucket-contiguous).
    #pragma unroll
    for (int q = 0; q < 16; ++q) {
        const int idx = t * 16 + q;
        if (idx < nE) {
            const int b = dsts[q] / NPB;
            const int p = atomicAdd(&lcur[b], 1);
            stage[p] = ((unsigned long long)(unsigned)dsts[q] << 32) | (unsigned)srcs[q];
        }
    }
    __syncthreads();

    // Coalesced write-out at reserved offsets.
    for (int i = t; i < nE; i += 256) {
        const unsigned long long v = stage[i];
        const int b = (int)(v >> 32) / NPB;
        const int p = res[b] + (i - lexcl[b]);
        if (p < BKT_CAP) binned[(size_t)b * BKT_CAP + p] = v;
    }
}

// ---- fused: one block per bucket (49 nodes). LDS float-atomic gather-
//      accumulate, then mean + W^T epilogue, direct out write ----
__global__ __launch_bounds__(256) void fused_kernel(
    const unsigned long long* __restrict__ binned,
    const int* __restrict__ cursor,
    const float* __restrict__ x,
    const float4* __restrict__ wt4,   // [16][128]: (k4,o) = W[o][4k4..4k4+3]
    float* __restrict__ out)
{
    __shared__ float lsum[NPB * LSTRIDE];  // 13.3 KB
    __shared__ int   lcnt[NPB];

    const int b    = blockIdx.x;
    const int lo   = b * NPB;
    const int t    = threadIdx.x;
    const int wave = t >> 6;
    const int lane = t & 63;
    const int grp  = lane >> 4;   // which of 4 edges per iteration
    const int ch4  = lane & 15;   // float4 channel slot

    for (int i = t; i < NPB * LSTRIDE; i += 256) lsum[i] = 0.f;
    if (t < NPB) lcnt[t] = 0;
    __syncthreads();

    const int cnt = min(cursor[b], BKT_CAP);

    // Edge phase: wave-interleaved 64-edge chunks; 4 edges per iteration,
    // 16 lanes x float4 per source row, ds_add_f32 accumulate.
    for (int base = wave * 64; base < cnt; base += 256) {
        const int m = min(cnt - base, 64);
        unsigned long long ev = 0;
        if (lane < m) ev = binned[(size_t)b * BKT_CAP + base + lane];
        const int src_ = (int)(ev & 0xffffffffu);
        const int loc_ = (int)(ev >> 32) - lo;
        const int nIt = (m + 3) >> 2;
        for (int it = 0; it < nIt; ++it) {
            const int e = it * 4 + grp;           // e <= 63
            const int s = __shfl(src_, e, 64);
            const int l = __shfl(loc_, e, 64);
            const float4 v = *reinterpret_cast<const float4*>(x + (size_t)s * IN_CH + ch4 * 4);
            if (e < m) {
                float* p = &lsum[l * LSTRIDE + ch4 * 4];
                atomicAdd(p + 0, v.x);
                atomicAdd(p + 1, v.y);
                atomicAdd(p + 2, v.z);
                atomicAdd(p + 3, v.w);
                if (ch4 == 0) atomicAdd(&lcnt[l], 1);
            }
        }
    }
    __syncthreads();

    // Epilogue: wave w -> nodes [w*13, w*13+13); lane -> out channels {lane, lane+64}.
    float acc[13][2];
    #pragma unroll
    for (int j = 0; j < 13; ++j) { acc[j][0] = 0.f; acc[j][1] = 0.f; }
    const int lbase = wave * 13;
    #pragma unroll
    for (int k4 = 0; k4 < 16; ++k4) {
        const float4 w0 = wt4[k4 * 128 + lane];        // coalesced L2 read
        const float4 w1 = wt4[k4 * 128 + 64 + lane];
        #pragma unroll
        for (int j = 0; j < 13; ++j) {
            const int lc = min(lbase + j, NPB - 1);    // clamp for LDS bounds
            const float4 a = *reinterpret_cast<const float4*>(&lsum[lc * LSTRIDE + k4 * 4]);  // broadcast
            acc[j][0] += a.x * w0.x + a.y * w0.y + a.z * w0.z + a.w * w0.w;
            acc[j][1] += a.x * w1.x + a.y * w1.y + a.z * w1.z + a.w * w1.w;
        }
    }
    #pragma unroll
    for (int j = 0; j < 13; ++j) {
        const int loc = lbase + j;
        const int n = lo + loc;
        if (loc < NPB && n < N_NODES) {
            const float inv = 1.0f / fmaxf((float)lcnt[loc], 1.0f);
            const size_t row = (size_t)n * HID_CH;
            out[row + lane]      = acc[j][0] * inv;
            out[row + 64 + lane] = acc[j][1] * inv;
        }
    }
}

extern "C" void kernel_launch(void* const* d_in, const int* in_sizes, int n_in,
                              void* d_out, int out_size, void* d_ws, size_t ws_size,
                              hipStream_t stream) {
    const float* x   = (const float*)d_in[0];
    const int*   ei  = (const int*)  d_in[1];
    const float* W   = (const float*)d_in[2];
    float*       out = (float*)d_out;

    // ws layout: binned (8 MB, 8B-aligned), cursor (4 KB), wt4 (32 KB, 16B-aligned)
    unsigned long long* binned = (unsigned long long*)d_ws;
    int*    cursor = (int*)(binned + (size_t)NBKT * BKT_CAP);
    float4* wt4    = (float4*)(cursor + NBKT);

    prep_kernel<<<9, 256, 0, stream>>>(W, wt4, cursor);
    bin_kernel<<<NBIN, 256, 0, stream>>>(ei, cursor, binned);
    fused_kernel<<<NBKT, 256, 0, stream>>>(binned, cursor, x, wt4, out);
}

// Round 10
// 437.508 us; speedup vs baseline: 1.3900x; 1.3900x over previous
//
#include <hip/hip_runtime.h>

// GraphSAGE mean-aggregate + linear (no bias): out = segment_mean(x[src] by dst) @ W^T
// x: [50000, 64] f32, edge_index: [2, 800000] int32, W: [128, 64] f32,
// out: [50000, 128] f32.
//
// Pipeline (3 dispatches):
//   memset(cursor) -> bin (bucket sort by dst/49 into 1024 buckets, LDS-staged)
//   -> fused (per bucket: LDS float-atomic scatter-accumulate of x rows, then
//      mean + W^T epilogue with W in LDS, 4-node register batches, direct out).

constexpr int N_NODES = 50000;
constexpr int N_EDGES = 800000;
constexpr int IN_CH   = 64;
constexpr int HID_CH  = 128;

constexpr int NBKT    = 1024;
constexpr int NPB     = 49;          // nodes per bucket; 1024*49 = 50176 >= 50000
constexpr int BKT_CAP = 1024;        // mean 781, sigma ~28 -> +8.7 sigma headroom
constexpr int CHUNK   = 4096;        // edges per binning block
constexpr int NBIN    = (N_EDGES + CHUNK - 1) / CHUNK;  // 196
constexpr int LSTRIDE = 68;          // lsum row stride (floats): 16B-aligned, +4 bank shift/row

// ---- bin: bucket-bin edges into 1024 buckets. LDS histogram + local sort,
//      coalesced write-out; rotated global-cursor reservation order ----
__global__ __launch_bounds__(256) void bin_kernel(
    const int* __restrict__ ei,
    int* __restrict__ cursor,                       // [NBKT], zeroed
    unsigned long long* __restrict__ binned)        // [NBKT][BKT_CAP] (dst<<32)|src
{
    __shared__ int hist[NBKT];
    __shared__ int lexcl[NBKT];
    __shared__ int lcur[NBKT];
    __shared__ int res[NBKT];
    __shared__ int scan2[256];
    __shared__ unsigned long long stage[CHUNK];

    const int t  = threadIdx.x;
    const int e0 = blockIdx.x * CHUNK;
    const int nE = min(N_EDGES - e0, CHUNK);

    #pragma unroll
    for (int i = 0; i < 4; ++i) hist[t + i * 256] = 0;
    __syncthreads();

    int srcs[16], dsts[16];
    #pragma unroll
    for (int q = 0; q < 4; ++q) {
        const int idx = t * 16 + q * 4;
        if (idx < nE) {  // nE % 4 == 0 always
            const int4 s4 = *reinterpret_cast<const int4*>(ei + e0 + idx);
            const int4 d4 = *reinterpret_cast<const int4*>(ei + N_EDGES + e0 + idx);
            srcs[q * 4 + 0] = s4.x; srcs[q * 4 + 1] = s4.y;
            srcs[q * 4 + 2] = s4.z; srcs[q * 4 + 3] = s4.w;
            dsts[q * 4 + 0] = d4.x; dsts[q * 4 + 1] = d4.y;
            dsts[q * 4 + 2] = d4.z; dsts[q * 4 + 3] = d4.w;
            atomicAdd(&hist[d4.x / NPB], 1);
            atomicAdd(&hist[d4.y / NPB], 1);
            atomicAdd(&hist[d4.z / NPB], 1);
            atomicAdd(&hist[d4.w / NPB], 1);
        } else {
            srcs[q*4+0]=srcs[q*4+1]=srcs[q*4+2]=srcs[q*4+3]=0;
            dsts[q*4+0]=dsts[q*4+1]=dsts[q*4+2]=dsts[q*4+3]=0;
        }
    }
    __syncthreads();

    // Exclusive scan over 1024 buckets: thread t owns buckets 4t..4t+3.
    const int b0 = t * 4;
    const int h0 = hist[b0], h1 = hist[b0 + 1], h2 = hist[b0 + 2], h3 = hist[b0 + 3];
    const int hs = h0 + h1 + h2 + h3;
    scan2[t] = hs;
    __syncthreads();
    for (int off = 1; off < 256; off <<= 1) {
        const int u = (t >= off) ? scan2[t - off] : 0;
        __syncthreads();
        scan2[t] += u;
        __syncthreads();
    }
    const int base = scan2[t] - hs;
    lexcl[b0]     = base;                lcur[b0]     = base;
    lexcl[b0 + 1] = base + h0;           lcur[b0 + 1] = base + h0;
    lexcl[b0 + 2] = base + h0 + h1;      lcur[b0 + 2] = base + h0 + h1;
    lexcl[b0 + 3] = base + h0 + h1 + h2; lcur[b0 + 3] = base + h0 + h1 + h2;

    // Reserve global space; rotate visit order to spread atomic contention.
    const int rot = (blockIdx.x * 97) & (NBKT - 1);
    #pragma unroll
    for (int i = 0; i < 4; ++i) {
        const int b = (b0 + i + rot) & (NBKT - 1);
        const int hv = hist[b];
        res[b] = (hv > 0) ? atomicAdd(&cursor[b], hv) : 0;
    }
    __syncthreads();

    // Local sort into stage (bucket-contiguous).
    #pragma unroll
    for (int q = 0; q < 16; ++q) {
        const int idx = t * 16 + q;
        if (idx < nE) {
            const int b = dsts[q] / NPB;
            const int p = atomicAdd(&lcur[b], 1);
            stage[p] = ((unsigned long long)(unsigned)dsts[q] << 32) | (unsigned)srcs[q];
        }
    }
    __syncthreads();

    // Coalesced write-out at reserved offsets.
    for (int i = t; i < nE; i += 256) {
        const unsigned long long v = stage[i];
        const int b = (int)(v >> 32) / NPB;
        const int p = res[b] + (i - lexcl[b]);
        if (p < BKT_CAP) binned[(size_t)b * BKT_CAP + p] = v;
    }
}

// ---- fused: one block per bucket (49 nodes). LDS float-atomic gather-
//      accumulate, then mean + W^T epilogue (W in LDS, 4-node batches) ----
__global__ __launch_bounds__(256) void fused_kernel(
    const unsigned long long* __restrict__ binned,
    const int* __restrict__ cursor,
    const float* __restrict__ x,
    const float* __restrict__ W,
    float* __restrict__ out)
{
    __shared__ float4 sW4[16][HID_CH + 1];   // [k4][o] = W[o][4k4..4k4+3]; 33 KB
    __shared__ float  lsum[NPB * LSTRIDE];   // 13.3 KB
    __shared__ int    lcnt[NPB];

    const int b    = blockIdx.x;
    const int lo   = b * NPB;
    const int t    = threadIdx.x;
    const int wave = t >> 6;
    const int lane = t & 63;
    const int grp  = lane >> 4;   // which of 4 edges per iteration
    const int ch4  = lane & 15;   // float4 channel slot

    // Stage W into LDS (coalesced; overlaps with lsum zeroing).
    #pragma unroll
    for (int r = 0; r < 8; ++r) {
        const int i = t + r * 256;
        const int o = i >> 4, k4 = i & 15;
        sW4[k4][o] = *reinterpret_cast<const float4*>(W + (size_t)o * IN_CH + k4 * 4);
    }
    for (int i = t; i < NPB * LSTRIDE; i += 256) lsum[i] = 0.f;
    if (t < NPB) lcnt[t] = 0;
    __syncthreads();

    const int cnt = min(cursor[b], BKT_CAP);

    // Edge phase: wave-interleaved 64-edge chunks; 4 edges per iteration,
    // 16 lanes x float4 per source row, ds_add_f32 accumulate.
    for (int base = wave * 64; base < cnt; base += 256) {
        const int m = min(cnt - base, 64);
        unsigned long long ev = 0;
        if (lane < m) ev = binned[(size_t)b * BKT_CAP + base + lane];
        const int src_ = (int)(ev & 0xffffffffu);
        const int loc_ = (int)(ev >> 32) - lo;
        const int nIt = (m + 3) >> 2;
        for (int it = 0; it < nIt; ++it) {
            const int e = it * 4 + grp;           // e <= 63
            const int s = __shfl(src_, e, 64);
            const int l = __shfl(loc_, e, 64);
            const float4 v = *reinterpret_cast<const float4*>(x + (size_t)s * IN_CH + ch4 * 4);
            if (e < m) {
                float* p = &lsum[l * LSTRIDE + ch4 * 4];
                atomicAdd(p + 0, v.x);
                atomicAdd(p + 1, v.y);
                atomicAdd(p + 2, v.z);
                atomicAdd(p + 3, v.w);
                if (ch4 == 0) atomicAdd(&lcnt[l], 1);
            }
        }
    }
    __syncthreads();

    // Epilogue: wave w owns nodes [w*13, w*13+13); 4-node register batches.
    // lane -> out channels {lane, lane+64}.
    const int lbase = wave * 13;
    for (int j0 = 0; j0 < 13; j0 += 4) {         // batches 4,4,4,1
        float acc[4][2] = {{0.f,0.f},{0.f,0.f},{0.f,0.f},{0.f,0.f}};
        #pragma unroll
        for (int k4 = 0; k4 < 16; ++k4) {
            const float4 w0 = sW4[k4][lane];
            const float4 w1 = sW4[k4][lane + 64];
            #pragma unroll
            for (int jj = 0; jj < 4; ++jj) {
                const int lc = min(lbase + j0 + jj, NPB - 1);  // clamp (mask on write)
                const float4 a = *reinterpret_cast<const float4*>(&lsum[lc * LSTRIDE + k4 * 4]);  // broadcast
                acc[jj][0] += a.x * w0.x + a.y * w0.y + a.z * w0.z + a.w * w0.w;
                acc[jj][1] += a.x * w1.x + a.y * w1.y + a.z * w1.z + a.w * w1.w;
            }
        }
        #pragma unroll
        for (int jj = 0; jj < 4; ++jj) {
            const int loc = lbase + j0 + jj;
            const int n = lo + loc;
            if (loc < NPB && n < N_NODES) {
                const float inv = 1.0f / fmaxf((float)lcnt[loc], 1.0f);
                const size_t row = (size_t)n * HID_CH;
                out[row + lane]      = acc[jj][0] * inv;
                out[row + 64 + lane] = acc[jj][1] * inv;
            }
        }
    }
}

extern "C" void kernel_launch(void* const* d_in, const int* in_sizes, int n_in,
                              void* d_out, int out_size, void* d_ws, size_t ws_size,
                              hipStream_t stream) {
    const float* x   = (const float*)d_in[0];
    const int*   ei  = (const int*)  d_in[1];
    const float* W   = (const float*)d_in[2];
    float*       out = (float*)d_out;

    // ws layout: binned (8 MB, 8B-aligned), cursor (4 KB)
    unsigned long long* binned = (unsigned long long*)d_ws;
    int* cursor = (int*)(binned + (size_t)NBKT * BKT_CAP);

    hipMemsetAsync(cursor, 0, NBKT * sizeof(int), stream);
    bin_kernel<<<NBIN, 256, 0, stream>>>(ei, cursor, binned);
    fused_kernel<<<NBKT, 256, 0, stream>>>(binned, cursor, x, W, out);
}

// Round 11
// 141.815 us; speedup vs baseline: 4.2881x; 3.0851x over previous
//
#include <hip/hip_runtime.h>

// GraphSAGE mean-aggregate + linear (no bias): out = segment_mean(x[src] by dst) @ W^T
// x: [50000, 64] f32, edge_index: [2, 800000] int32, W: [128, 64] f32,
// out: [50000, 128] f32.
//
// Pipeline (4 dispatches) — R5 structure + gather/gemm fusion:
//   memset(cursor) -> bin (bucket sort by dst/196, LDS-staged, coalesced)
//   -> csr_build (per-bucket local CSR in LDS, coalesced)
//   -> gather_fused (one wave per 4 nodes: register gather + butterfly merge,
//      then mean + W^T epilogue with W in a 33 KB LDS tile, direct out write).

constexpr int N_NODES = 50000;
constexpr int N_EDGES = 800000;
constexpr int IN_CH   = 64;
constexpr int HID_CH  = 128;

constexpr int NBKT          = 256;
constexpr int NODES_PER_BKT = 196;   // 256*196 = 50176 >= 50000; bucket = dst/196
constexpr int BKT_CAP       = 4096;  // mean 3125, sigma ~56 -> +17 sigma headroom
constexpr int CHUNK         = 4096;  // edges per binning block
constexpr int NBIN          = (N_EDGES + CHUNK - 1) / CHUNK;  // 196

// ---- pass 1: bucket-bin edges. LDS histogram + local sort, coalesced out ----
__global__ __launch_bounds__(256) void bin_kernel(
    const int* __restrict__ ei,
    int* __restrict__ cursor,                       // [NBKT], zeroed
    unsigned long long* __restrict__ binned)        // [NBKT][BKT_CAP] (dst<<32)|src
{
    __shared__ int hist[NBKT];
    __shared__ int scan[NBKT];
    __shared__ int lexcl[NBKT];
    __shared__ int lcur[NBKT];
    __shared__ int res[NBKT];
    __shared__ unsigned long long stage[CHUNK];

    const int t  = threadIdx.x;
    const int e0 = blockIdx.x * CHUNK;
    const int nE = min(N_EDGES - e0, CHUNK);

    hist[t] = 0;
    __syncthreads();

    int srcs[16], dsts[16];
    #pragma unroll
    for (int q = 0; q < 4; ++q) {
        const int idx = t * 16 + q * 4;
        if (idx < nE) {  // nE % 4 == 0 always
            const int4 s4 = *reinterpret_cast<const int4*>(ei + e0 + idx);
            const int4 d4 = *reinterpret_cast<const int4*>(ei + N_EDGES + e0 + idx);
            srcs[q * 4 + 0] = s4.x; srcs[q * 4 + 1] = s4.y;
            srcs[q * 4 + 2] = s4.z; srcs[q * 4 + 3] = s4.w;
            dsts[q * 4 + 0] = d4.x; dsts[q * 4 + 1] = d4.y;
            dsts[q * 4 + 2] = d4.z; dsts[q * 4 + 3] = d4.w;
            atomicAdd(&hist[d4.x / NODES_PER_BKT], 1);
            atomicAdd(&hist[d4.y / NODES_PER_BKT], 1);
            atomicAdd(&hist[d4.z / NODES_PER_BKT], 1);
            atomicAdd(&hist[d4.w / NODES_PER_BKT], 1);
        } else {
            srcs[q*4+0]=srcs[q*4+1]=srcs[q*4+2]=srcs[q*4+3]=0;
            dsts[q*4+0]=dsts[q*4+1]=dsts[q*4+2]=dsts[q*4+3]=0;
        }
    }
    __syncthreads();

    const int hv = hist[t];
    scan[t] = hv;
    __syncthreads();
    for (int off = 1; off < NBKT; off <<= 1) {
        const int u = (t >= off) ? scan[t - off] : 0;
        __syncthreads();
        scan[t] += u;
        __syncthreads();
    }
    const int myExcl = scan[t] - hv;
    lexcl[t] = myExcl;
    lcur[t]  = myExcl;
    res[t]   = (hv > 0) ? atomicAdd(&cursor[t], hv) : 0;
    __syncthreads();

    #pragma unroll
    for (int q = 0; q < 16; ++q) {
        const int idx = t * 16 + q;
        if (idx < nE) {
            const int b = dsts[q] / NODES_PER_BKT;
            const int p = atomicAdd(&lcur[b], 1);
            stage[p] = ((unsigned long long)(unsigned)dsts[q] << 32) | (unsigned)srcs[q];
        }
    }
    __syncthreads();

    for (int i = t; i < nE; i += 256) {
        const unsigned long long v = stage[i];
        const int b = (int)(v >> 32) / NODES_PER_BKT;
        const int p = res[b] + (i - lexcl[b]);
        if (p < BKT_CAP) binned[(size_t)b * BKT_CAP + p] = v;
    }
}

// ---- pass 2: one block per bucket -> offs, csr_src (all coalesced) ----
__global__ __launch_bounds__(256) void csr_build_kernel(
    const unsigned long long* __restrict__ binned,
    const int* __restrict__ cursor,
    int* __restrict__ offs,      // [N_NODES+1]
    int* __restrict__ csr_src)   // [N_EDGES]
{
    __shared__ int bsum[NBKT];
    __shared__ int ldeg[NODES_PER_BKT];
    __shared__ int lscan[NBKT];
    __shared__ int lcur[NODES_PER_BKT];
    __shared__ int stage_src[BKT_CAP];

    const int b = blockIdx.x;
    const int t = threadIdx.x;

    // scan of bucket counts -> edge base for this bucket
    const int cAll = min(cursor[t], BKT_CAP);
    bsum[t] = cAll;
    if (t < NODES_PER_BKT) ldeg[t] = 0;
    __syncthreads();
    for (int off = 1; off < NBKT; off <<= 1) {
        const int u = (t >= off) ? bsum[t - off] : 0;
        __syncthreads();
        bsum[t] += u;
        __syncthreads();
    }
    const int cnt   = min(cursor[b], BKT_CAP);
    const int ebase = bsum[b] - cnt;
    const int nodeBase = b * NODES_PER_BKT;

    unsigned long long ev[16];
    #pragma unroll
    for (int q = 0; q < 16; ++q) {
        const int i = t + q * 256;
        ev[q] = 0;
        if (i < cnt) {
            ev[q] = binned[(size_t)b * BKT_CAP + i];
            atomicAdd(&ldeg[(int)(ev[q] >> 32) - nodeBase], 1);
        }
    }
    __syncthreads();

    const int dv = (t < NODES_PER_BKT) ? ldeg[t] : 0;
    lscan[t] = dv;
    __syncthreads();
    for (int off = 1; off < NBKT; off <<= 1) {
        const int u = (t >= off) ? lscan[t - off] : 0;
        __syncthreads();
        lscan[t] += u;
        __syncthreads();
    }
    const int nNodes = min(N_NODES - nodeBase, NODES_PER_BKT);
    if (t < nNodes) {
        const int excl = lscan[t] - dv;
        offs[nodeBase + t] = ebase + excl;
        lcur[t] = excl;
    }
    if (b == NBKT - 1 && t == 0) offs[N_NODES] = N_EDGES;
    __syncthreads();

    #pragma unroll
    for (int q = 0; q < 16; ++q) {
        const int i = t + q * 256;
        if (i < cnt) {
            const int loc = (int)(ev[q] >> 32) - nodeBase;
            const int p = atomicAdd(&lcur[loc], 1);
            stage_src[p] = (int)(ev[q] & 0xffffffffu);
        }
    }
    __syncthreads();

    for (int i = t; i < cnt; i += 256) {
        csr_src[ebase + i] = stage_src[i];
    }
}

// ---- pass 3 (fused): one wave per 4 consecutive nodes. Register gather
//      (16 lanes x float4 per row, 16 edges in flight) + butterfly merge,
//      then mean + W^T epilogue from LDS-staged W. ----
__global__ __launch_bounds__(256) void gather_fused_kernel(
    const float* __restrict__ x,
    const int*   __restrict__ csr_src,
    const int*   __restrict__ offs,
    const float* __restrict__ W,
    float*       __restrict__ out)
{
    __shared__ float4 sW4[16][HID_CH + 1];  // [k4][o] = W[o][4k4..4k4+3]; 33 KB
    __shared__ float4 sM[4][16];            // per-wave scaled mean staging

    const int t = threadIdx.x;
    #pragma unroll
    for (int r = 0; r < 8; ++r) {
        const int i = t + r * 256;
        const int o = i >> 4, k4 = i & 15;
        sW4[k4][o] = *reinterpret_cast<const float4*>(W + (size_t)o * IN_CH + k4 * 4);
    }
    __syncthreads();

    const int wave = t >> 6;
    const int lane = t & 63;
    const int grp  = lane >> 4;
    const int ch4  = lane & 15;
    const int wid  = blockIdx.x * 4 + wave;   // grid 3125 -> 12500 waves, 4 nodes each

    #pragma unroll 1
    for (int j = 0; j < 4; ++j) {
        const int n = wid * 4 + j;            // consecutive nodes per wave
        const int start = offs[n];
        const int end   = offs[n + 1];
        const int d     = end - start;

        float a0 = 0.f, a1 = 0.f, a2 = 0.f, a3 = 0.f;
        for (int base = start; base < end; base += 64) {
            const int cnt = min(end - base, 64);
            int idx = 0;
            if (lane < cnt) idx = csr_src[base + lane];
            const int nIt = (cnt + 3) >> 2;
            for (int i = 0; i < nIt; i += 4) {
                const int e0 = 4 * i + grp;
                const int e1 = e0 + 4, e2 = e0 + 8, e3 = e0 + 12;
                const int s0 = __shfl(idx, e0 & 63, 64);
                const int s1 = __shfl(idx, e1 & 63, 64);
                const int s2 = __shfl(idx, e2 & 63, 64);
                const int s3 = __shfl(idx, e3 & 63, 64);
                const float f0 = (e0 < cnt) ? 1.f : 0.f;
                const float f1 = (e1 < cnt) ? 1.f : 0.f;
                const float f2 = (e2 < cnt) ? 1.f : 0.f;
                const float f3 = (e3 < cnt) ? 1.f : 0.f;
                const float4 v0 = *reinterpret_cast<const float4*>(x + (size_t)s0 * IN_CH + ch4 * 4);
                const float4 v1 = *reinterpret_cast<const float4*>(x + (size_t)s1 * IN_CH + ch4 * 4);
                const float4 v2 = *reinterpret_cast<const float4*>(x + (size_t)s2 * IN_CH + ch4 * 4);
                const float4 v3 = *reinterpret_cast<const float4*>(x + (size_t)s3 * IN_CH + ch4 * 4);
                a0 = fmaf(f0, v0.x, a0); a1 = fmaf(f0, v0.y, a1);
                a2 = fmaf(f0, v0.z, a2); a3 = fmaf(f0, v0.w, a3);
                a0 = fmaf(f1, v1.x, a0); a1 = fmaf(f1, v1.y, a1);
                a2 = fmaf(f1, v1.z, a2); a3 = fmaf(f1, v1.w, a3);
                a0 = fmaf(f2, v2.x, a0); a1 = fmaf(f2, v2.y, a1);
                a2 = fmaf(f2, v2.z, a2); a3 = fmaf(f2, v2.w, a3);
                a0 = fmaf(f3, v3.x, a0); a1 = fmaf(f3, v3.y, a1);
                a2 = fmaf(f3, v3.z, a2); a3 = fmaf(f3, v3.w, a3);
            }
        }
        // Merge the 4 edge groups: lanes 0-15 end with full channel sums.
        #pragma unroll
        for (int m = 16; m <= 32; m <<= 1) {
            a0 += __shfl_xor(a0, m, 64);
            a1 += __shfl_xor(a1, m, 64);
            a2 += __shfl_xor(a2, m, 64);
            a3 += __shfl_xor(a3, m, 64);
        }
        const float inv = 1.0f / fmaxf((float)d, 1.0f);
        if (lane < 16) {
            float4 r{a0 * inv, a1 * inv, a2 * inv, a3 * inv};
            sM[wave][ch4] = r;
        }
        // Same-wave LDS write -> read: drain DS queue; memory clobber orders
        // the following ds_reads; sched_barrier pins codegen.
        __asm__ volatile("s_waitcnt lgkmcnt(0)" ::: "memory");
        __builtin_amdgcn_sched_barrier(0);

        float o0 = 0.f, o1 = 0.f;
        #pragma unroll
        for (int k4 = 0; k4 < 16; ++k4) {
            const float4 w0 = sW4[k4][lane];
            const float4 w1 = sW4[k4][lane + 64];
            const float4 a  = sM[wave][k4];   // broadcast read
            o0 += a.x * w0.x + a.y * w0.y + a.z * w0.z + a.w * w0.w;
            o1 += a.x * w1.x + a.y * w1.y + a.z * w1.z + a.w * w1.w;
        }
        const size_t row = (size_t)n * HID_CH;
        out[row + lane]      = o0;
        out[row + 64 + lane] = o1;
    }
}

extern "C" void kernel_launch(void* const* d_in, const int* in_sizes, int n_in,
                              void* d_out, int out_size, void* d_ws, size_t ws_size,
                              hipStream_t stream) {
    const float* x   = (const float*)d_in[0];
    const int*   ei  = (const int*)  d_in[1];
    const float* W   = (const float*)d_in[2];
    float*       out = (float*)d_out;

    // ws layout: binned (8 MB, 8B-aligned), cursor, offs (padded), csr_src
    unsigned long long* binned = (unsigned long long*)d_ws;        // NBKT*BKT_CAP
    int* cursor  = (int*)(binned + (size_t)NBKT * BKT_CAP);        // [NBKT]
    int* offs    = cursor + NBKT;                                  // [N_NODES+1] pad->50004
    int* csr_src = offs + 50004;                                   // [N_EDGES]

    hipMemsetAsync(cursor, 0, NBKT * sizeof(int), stream);
    bin_kernel<<<NBIN, 256, 0, stream>>>(ei, cursor, binned);
    csr_build_kernel<<<NBKT, 256, 0, stream>>>(binned, cursor, offs, csr_src);
    gather_fused_kernel<<<N_NODES / 16, 256, 0, stream>>>(x, csr_src, offs, W, out);
}